// Round 7
// baseline (691.460 us; speedup 1.0000x reference)
//
#include <hip/hip_runtime.h>
#include <hip/hip_bf16.h>
#include <cstdint>
#include <cstddef>

// Problem constants (from reference)
#define NBAGS  16
#define NNODES 5000
#define NEDGES 160000
#define DIN    128
#define DENC   256   // == D_GNN
#define DFC    128
#define NCLS   2

#define TPB 40   // row-tiles of 128 per bag (40*128 = 5120 >= 5000)

typedef __attribute__((ext_vector_type(8))) short short8;
typedef __attribute__((ext_vector_type(4))) float f32x4;

static __device__ __forceinline__ ushort f2b(float v) {
    __hip_bfloat16 b = __float2bfloat16(v);   // RNE
    return *reinterpret_cast<ushort*>(&b);
}

// ---------------------------------------------------------------------------
// bf16 MFMA GEMM, bag-pinned grid: 8 bags x 40 row-tiles x 2 col-halves =
// 640 blocks; bag = blockIdx&7 so bag b runs on XCD b%8 — same XCD that
// produced its A-rows (agg/gemm all share this mapping) and will consume C.
// C[bagRows x 256] = act( A1@W1t^T (+ A2@W2t^T) + bias ), bf16 out.
// REDUCE=true: column-sum relu() into emb[gbag][col] (no straddle: per-bag tiles).
// BM=128(x40 tiles), BN=128, BK=32; 4 waves, 4x4 mfma_f32_16x16x32_bf16 each.
// ---------------------------------------------------------------------------
template<bool DUAL, bool RELU, bool REDUCE>
__global__ __launch_bounds__(256)
void gemm_bf16_kernel(const ushort* __restrict__ A1, const ushort* __restrict__ Wt1,
                      const ushort* __restrict__ A2, const ushort* __restrict__ Wt2,
                      const float* __restrict__ bias, ushort* __restrict__ C,
                      float* __restrict__ emb, int K, int batchBase)
{
    constexpr int LDSP = 40;
    __shared__ __align__(16) ushort As[128 * LDSP];
    __shared__ __align__(16) ushort Bs[128 * LDSP];

    const int bx   = blockIdx.x;
    const int bag  = bx & 7;
    const int rem  = bx >> 3;          // 0..79
    const int col  = rem & 1;
    const int tile = rem >> 1;         // 0..39
    const int gbag = batchBase + bag;
    const size_t bagRow0 = (size_t)gbag * NNODES;
    const int rloc0 = tile * 128;      // local row offset within bag
    const int n0 = col * 128;

    const int tid  = threadIdx.x;
    const int wave = tid >> 6;
    const int lane = tid & 63;
    const int quad = lane >> 4;
    const int l16  = lane & 15;
    const int wm   = (wave >> 1) * 64;
    const int wn   = (wave & 1) * 64;

    f32x4 acc[4][4];
#pragma unroll
    for (int i = 0; i < 4; ++i)
#pragma unroll
        for (int j = 0; j < 4; ++j)
#pragma unroll
            for (int r = 0; r < 4; ++r) acc[i][j][r] = 0.f;

    const int sr = tid >> 1;           // staging row 0..127
    const int sk = (tid & 1) * 16;

    const int npass = DUAL ? 2 : 1;
    for (int pass = 0; pass < npass; ++pass) {
        const ushort* __restrict__ A = (DUAL && pass) ? A2 : A1;
        const ushort* __restrict__ W = (DUAL && pass) ? Wt2 : Wt1;

        for (int k0 = 0; k0 < K; k0 += 32) {
            {
                uint4 v0 = make_uint4(0, 0, 0, 0), v1 = make_uint4(0, 0, 0, 0);
                const int rl = rloc0 + sr;
                if (rl < NNODES) {
                    const uint4* src = (const uint4*)(A + (bagRow0 + rl) * K + k0 + sk);
                    v0 = src[0]; v1 = src[1];
                }
                *(uint4*)&As[sr * LDSP + sk]     = v0;
                *(uint4*)&As[sr * LDSP + sk + 8] = v1;
            }
            {
                const uint4* src = (const uint4*)(W + (size_t)(n0 + sr) * K + k0 + sk);
                *(uint4*)&Bs[sr * LDSP + sk]     = src[0];
                *(uint4*)&Bs[sr * LDSP + sk + 8] = src[1];
            }
            __syncthreads();

            short8 af[4], bf[4];
#pragma unroll
            for (int t = 0; t < 4; ++t) {
                af[t] = *(const short8*)&As[(wm + t * 16 + l16) * LDSP + quad * 8];
                bf[t] = *(const short8*)&Bs[(wn + t * 16 + l16) * LDSP + quad * 8];
            }
#pragma unroll
            for (int tm = 0; tm < 4; ++tm)
#pragma unroll
                for (int tn = 0; tn < 4; ++tn)
                    acc[tm][tn] = __builtin_amdgcn_mfma_f32_16x16x32_bf16(
                        af[tm], bf[tn], acc[tm][tn], 0, 0, 0);
            __syncthreads();
        }
    }

    if (!REDUCE) {
        // epilogue: bias + relu, bf16 store. C/D: row = quad*4+reg, col = l16
#pragma unroll
        for (int tm = 0; tm < 4; ++tm) {
            const int rbase = rloc0 + wm + tm * 16 + quad * 4;
#pragma unroll
            for (int reg = 0; reg < 4; ++reg) {
                const int rl = rbase + reg;
                if (rl < NNODES) {
#pragma unroll
                    for (int tn = 0; tn < 4; ++tn) {
                        const int gcol = n0 + wn + tn * 16 + l16;
                        float v = acc[tm][tn][reg] + bias[gcol];
                        if (RELU) v = fmaxf(v, 0.f);
                        C[(bagRow0 + rl) * 256 + gcol] = f2b(v);
                    }
                }
            }
        }
    } else {
        // fused column-sum epilogue -> emb[gbag] (single bag per block)
        __shared__ float red[128];
        if (tid < 128) red[tid] = 0.f;
        __syncthreads();
#pragma unroll
        for (int tn = 0; tn < 4; ++tn) {
            const int cl = wn + tn * 16 + l16;            // 0..127
            const float bv = bias[n0 + cl];
            float p = 0.f;
#pragma unroll
            for (int tm = 0; tm < 4; ++tm) {
#pragma unroll
                for (int reg = 0; reg < 4; ++reg) {
                    const int rl = rloc0 + wm + tm * 16 + quad * 4 + reg;
                    float v = acc[tm][tn][reg] + bv;
                    if (RELU) v = fmaxf(v, 0.f);
                    if (rl < NNODES) p += v;
                }
            }
            atomicAdd(&red[cl], p);
        }
        __syncthreads();
        if (tid < 128)
            atomicAdd(&emb[gbag * DENC + n0 + tid], red[tid]);
    }
}

// ---------------------------------------------------------------------------
// Weight convert+transpose: Wt[n*K+k] = bf16(W[k*256+n])
// ---------------------------------------------------------------------------
__global__ __launch_bounds__(256)
void wt_transpose_kernel(const float* __restrict__ W, ushort* __restrict__ Wt, int K)
{
    const int idx = blockIdx.x * 256 + threadIdx.x;
    if (idx < 256 * K) {
        const int n = idx / K;
        const int k = idx - n * K;
        Wt[idx] = f2b(W[k * 256 + n]);
    }
}

// ---------------------------------------------------------------------------
// bag->XCD swizzle helper (16 bags: two halves of 8, bag = r&7 (+8))
// ---------------------------------------------------------------------------
static __device__ __forceinline__ void bag_chunk16(int bx, int bpb, int& bag, int& chunk)
{
    const int half = 8 * bpb;
    const int hi = (bx >= half) ? 1 : 0;
    const int r = bx - hi * half;
    bag = (r & 7) + hi * 8;
    chunk = r >> 3;
}

// x (fp32) -> bf16, bag-swizzled so xb lands in bag's XCD L2.
// grid = 16 * 625 blocks; 625*256*4 = 640000 elems per bag (exact).
__global__ __launch_bounds__(256)
void cvt_bf16_kernel(const float* __restrict__ x, ushort* __restrict__ xb)
{
    int bag, chunk;
    bag_chunk16(blockIdx.x, 625, bag, chunk);
    const size_t base = (size_t)bag * (NNODES * DIN / 4);
    const int i = chunk * 256 + threadIdx.x;
    const float4 v = ((const float4*)x)[base + i];
    ushort4 o;
    o.x = f2b(v.x); o.y = f2b(v.y); o.z = f2b(v.z); o.w = f2b(v.w);
    ((ushort4*)xb)[base + i] = o;
}

// ---------------------------------------------------------------------------
// CSR build: count -> scan -> fill. edges laid out [bag][2][E], int32.
// Bag->XCD swizzle keeps each bag's cnt/fillc/colidx in ONE XCD's L2.
// Edge streams loaded non-temporally. colidx uint16 (src < 5000).
// scan writes fillc=rowptr so fill's atomicAdd returns absolute positions.
// ---------------------------------------------------------------------------
#define CSR_EPB 1024
#define CSR_BPB ((NEDGES + CSR_EPB - 1) / CSR_EPB)   // 157

__global__ __launch_bounds__(256)
void count_kernel(const int* __restrict__ edges, int* __restrict__ cnt)
{
    int bag, chunk;
    bag_chunk16(blockIdx.x, CSR_BPB, bag, chunk);
    const int* __restrict__ dstp = edges + (size_t)bag * 2 * NEDGES + NEDGES;
    int* __restrict__ cb = cnt + bag * NNODES;
    const int e0 = chunk * CSR_EPB + threadIdx.x;
    int d[4];
#pragma unroll
    for (int i = 0; i < 4; ++i) {
        const int e = e0 + i * 256;
        d[i] = (e < NEDGES) ? __builtin_nontemporal_load(&dstp[e]) : -1;
    }
#pragma unroll
    for (int i = 0; i < 4; ++i)
        if (d[i] >= 0) atomicAdd(&cb[d[i]], 1);
}

__global__ __launch_bounds__(1024)
void scan_kernel(const int* __restrict__ cnt, int* __restrict__ rowptr,
                 int* __restrict__ fillc)
{
    const int b = blockIdx.x;
    const int t = threadIdx.x;
    __shared__ int sh[1024];
    const int CH = 5;
    const int base = t * CH;
    int local[CH];
    int sum = 0;
#pragma unroll
    for (int i = 0; i < CH; ++i) {
        const int g = base + i;
        const int v = (g < NNODES) ? cnt[b * NNODES + g] : 0;
        local[i] = v; sum += v;
    }
    sh[t] = sum;
    __syncthreads();
    for (int off = 1; off < 1024; off <<= 1) {
        const int add = (t >= off) ? sh[t - off] : 0;
        __syncthreads();
        sh[t] += add;
        __syncthreads();
    }
    int run = sh[t] - sum;
#pragma unroll
    for (int i = 0; i < CH; ++i) {
        const int g = base + i;
        if (g < NNODES) {
            rowptr[b * (NNODES + 1) + g] = run;
            fillc[b * NNODES + g] = run;
        }
        run += local[i];
    }
    if (t == 1023) rowptr[b * (NNODES + 1) + NNODES] = run;
}

__global__ __launch_bounds__(256)
void fill_kernel(const int* __restrict__ edges, int* __restrict__ fillc,
                 ushort* __restrict__ colidx)
{
    int bag, chunk;
    bag_chunk16(blockIdx.x, CSR_BPB, bag, chunk);
    const int* __restrict__ eb = edges + (size_t)bag * 2 * NEDGES;
    int* __restrict__ fc = fillc + bag * NNODES;
    ushort* __restrict__ co = colidx + (size_t)bag * NEDGES;
    const int e0 = chunk * CSR_EPB + threadIdx.x;
    int src[4], dst[4];
#pragma unroll
    for (int i = 0; i < 4; ++i) {
        const int e = e0 + i * 256;
        if (e < NEDGES) {
            src[i] = __builtin_nontemporal_load(&eb[e]);
            dst[i] = __builtin_nontemporal_load(&eb[NEDGES + e]);
        } else dst[i] = -1;
    }
#pragma unroll
    for (int i = 0; i < 4; ++i) {
        if (dst[i] >= 0) {
            const int pos = atomicAdd(&fc[dst[i]], 1);
            co[pos] = (ushort)src[i];
        }
    }
}

// ---------------------------------------------------------------------------
// Mean aggregation (pull), bf16 in/out, fp32 accumulate.
// One WAVE per node: 64 lanes x uint2 = 512 B = one feature row per vmem.
// Batch of 8 bags, bag = blockIdx&7 -> each bag's 2.56 MB gather source sits
// in its own XCD's L2 (produced there by the bag-pinned GEMM).
// ---------------------------------------------------------------------------
__global__ __launch_bounds__(256)
void agg_mean_kernel(const ushort* __restrict__ X, const int* __restrict__ rowptr,
                     const ushort* __restrict__ colidx, ushort* __restrict__ M,
                     int batchBase)
{
    const int bx = blockIdx.x;
    const int bag = batchBase + (bx & 7);
    const int grp = bx >> 3;                  // 0..1249
    const int wave = threadIdx.x >> 6;
    const int lane = threadIdx.x & 63;
    const int node = grp * 4 + wave;

    const int* rp = rowptr + bag * (NNODES + 1);
    const int s = rp[node];
    const int e = rp[node + 1];
    const float inv = 1.0f / fmaxf((float)(e - s), 1.0f);
    const uint2* __restrict__ Xb = (const uint2*)(X + (size_t)bag * NNODES * DENC);
    const ushort* __restrict__ ci = colidx + (size_t)bag * NEDGES;

    float2 p0 = {0.f, 0.f}, p1 = {0.f, 0.f};
    int j = s;
    for (; j + 4 <= e; j += 4) {
        const int i0 = ci[j], i1 = ci[j + 1], i2 = ci[j + 2], i3 = ci[j + 3];
        const uint2 u0 = Xb[i0 * 64 + lane];
        const uint2 u1 = Xb[i1 * 64 + lane];
        const uint2 u2 = Xb[i2 * 64 + lane];
        const uint2 u3 = Xb[i3 * 64 + lane];
        p0.x += __uint_as_float(u0.x << 16); p0.y += __uint_as_float(u0.x & 0xffff0000u);
        p1.x += __uint_as_float(u0.y << 16); p1.y += __uint_as_float(u0.y & 0xffff0000u);
        p0.x += __uint_as_float(u1.x << 16); p0.y += __uint_as_float(u1.x & 0xffff0000u);
        p1.x += __uint_as_float(u1.y << 16); p1.y += __uint_as_float(u1.y & 0xffff0000u);
        p0.x += __uint_as_float(u2.x << 16); p0.y += __uint_as_float(u2.x & 0xffff0000u);
        p1.x += __uint_as_float(u2.y << 16); p1.y += __uint_as_float(u2.y & 0xffff0000u);
        p0.x += __uint_as_float(u3.x << 16); p0.y += __uint_as_float(u3.x & 0xffff0000u);
        p1.x += __uint_as_float(u3.y << 16); p1.y += __uint_as_float(u3.y & 0xffff0000u);
    }
    for (; j < e; ++j) {
        const uint2 u = Xb[ci[j] * 64 + lane];
        p0.x += __uint_as_float(u.x << 16); p0.y += __uint_as_float(u.x & 0xffff0000u);
        p1.x += __uint_as_float(u.y << 16); p1.y += __uint_as_float(u.y & 0xffff0000u);
    }
    uint2 o;
    o.x = (uint32_t)f2b(p0.x * inv) | ((uint32_t)f2b(p0.y * inv) << 16);
    o.y = (uint32_t)f2b(p1.x * inv) | ((uint32_t)f2b(p1.y * inv) << 16);
    ((uint2*)(M + ((size_t)bag * NNODES + node) * DENC))[lane] = o;
}

// ---------------------------------------------------------------------------
// classifier (fp32): out[b] = relu(emb[b]@Wc1 + bc1) @ Wc2 + bc2
// ---------------------------------------------------------------------------
__global__ __launch_bounds__(128)
void classifier_kernel(const float* __restrict__ emb, const float* __restrict__ Wc1,
                       const float* __restrict__ bc1, const float* __restrict__ Wc2,
                       const float* __restrict__ bc2, float* __restrict__ out)
{
    const int b = blockIdx.x;
    const int t = threadIdx.x;  // 128
    __shared__ float se[DENC];
    se[t] = emb[b * DENC + t];
    se[128 + t] = emb[b * DENC + 128 + t];
    __syncthreads();
    float h = bc1[t];
    for (int k = 0; k < DENC; ++k) h = fmaf(se[k], Wc1[k * DFC + t], h);
    h = fmaxf(h, 0.f);
    __shared__ float s0[128], s1[128];
    s0[t] = h * Wc2[t * NCLS + 0];
    s1[t] = h * Wc2[t * NCLS + 1];
    __syncthreads();
    for (int off = 64; off > 0; off >>= 1) {
        if (t < off) { s0[t] += s0[t + off]; s1[t] += s1[t + off]; }
        __syncthreads();
    }
    if (t == 0) {
        out[b * NCLS + 0] = s0[0] + bc2[0];
        out[b * NCLS + 1] = s1[0] + bc2[1];
    }
}

// ---------------------------------------------------------------------------
extern "C" void kernel_launch(void* const* d_in, const int* in_sizes, int n_in,
                              void* d_out, int out_size, void* d_ws, size_t ws_size,
                              hipStream_t stream)
{
    const float* x    = (const float*)d_in[0];
    const int*   edges= (const int*)d_in[1];   // int32 on device
    const float* We   = (const float*)d_in[2];
    const float* be   = (const float*)d_in[3];
    const float* Wl1  = (const float*)d_in[4];
    const float* bl1  = (const float*)d_in[5];
    const float* Wr1  = (const float*)d_in[6];
    const float* Wl2  = (const float*)d_in[7];
    const float* bl2  = (const float*)d_in[8];
    const float* Wr2  = (const float*)d_in[9];
    // d_in[10..12] = Wlp, blp, Wrp: dead (softmax over 1 cluster == 1)
    const float* Wc1  = (const float*)d_in[13];
    const float* bc1  = (const float*)d_in[14];
    const float* Wc2  = (const float*)d_in[15];
    const float* bc2  = (const float*)d_in[16];
    float* out = (float*)d_out;

    auto rnd = [](size_t v) { return (v + 255) & ~(size_t)255; };
    char* p = (char*)d_ws;
    auto alloc = [&](size_t bytes) -> char* {
        char* r = p; p += rnd(bytes); return r;
    };
    ushort* xb    = (ushort*)alloc((size_t)NBAGS * NNODES * DIN * 2);
    ushort* H     = (ushort*)alloc((size_t)NBAGS * NNODES * DENC * 2);  // h, then mean2
    ushort* Mb    = (ushort*)alloc((size_t)NBAGS * NNODES * DENC * 2);  // mean1
    ushort* Gb    = (ushort*)alloc((size_t)NBAGS * NNODES * DENC * 2);  // g1
    ushort* Wet   = (ushort*)alloc((size_t)256 * DIN * 2);
    ushort* Wl1t  = (ushort*)alloc((size_t)256 * DENC * 2);
    ushort* Wr1t  = (ushort*)alloc((size_t)256 * DENC * 2);
    ushort* Wl2t  = (ushort*)alloc((size_t)256 * DENC * 2);
    ushort* Wr2t  = (ushort*)alloc((size_t)256 * DENC * 2);
    int*    rowptr= (int*)   alloc((size_t)NBAGS * (NNODES + 1) * 4);
    int*    cnt   = (int*)   alloc((size_t)NBAGS * NNODES * 4);
    int*    fillc = (int*)   alloc((size_t)NBAGS * NNODES * 4);
    ushort* colidx= (ushort*)alloc((size_t)NBAGS * NEDGES * 2);
    float*  emb   = (float*) alloc((size_t)NBAGS * DENC * 4);

    // per-launch init (ws re-poisoned each call)
    hipMemsetAsync(emb, 0, (size_t)NBAGS * DENC * 4, stream);
    hipMemsetAsync(cnt, 0, (size_t)NBAGS * NNODES * 4, stream);

    // conversions
    cvt_bf16_kernel<<<NBAGS * 625, 256, 0, stream>>>(x, xb);
    wt_transpose_kernel<<<(256 * DIN + 255) / 256, 256, 0, stream>>>(We, Wet, DIN);
    wt_transpose_kernel<<<(256 * DENC + 255) / 256, 256, 0, stream>>>(Wl1, Wl1t, DENC);
    wt_transpose_kernel<<<(256 * DENC + 255) / 256, 256, 0, stream>>>(Wr1, Wr1t, DENC);
    wt_transpose_kernel<<<(256 * DENC + 255) / 256, 256, 0, stream>>>(Wl2, Wl2t, DENC);
    wt_transpose_kernel<<<(256 * DENC + 255) / 256, 256, 0, stream>>>(Wr2, Wr2t, DENC);

    // CSR build once (all 16 bags; bags b and b+8 share XCD b)
    count_kernel<<<NBAGS * CSR_BPB, 256, 0, stream>>>(edges, cnt);
    scan_kernel<<<NBAGS, 1024, 0, stream>>>(cnt, rowptr, fillc);
    fill_kernel<<<NBAGS * CSR_BPB, 256, 0, stream>>>(edges, fillc, colidx);

    // feature pipeline in two batches of 8 bags (1 bag per XCD)
    const int gemm_grid = 8 * TPB * 2;     // 640
    const int agg_grid  = 8 * (NNODES / 4);
    for (int base = 0; base < NBAGS; base += 8) {
        // encoder: H = relu(x @ We + be)
        gemm_bf16_kernel<false, true, false><<<gemm_grid, 256, 0, stream>>>(
            xb, Wet, nullptr, nullptr, be, H, nullptr, DIN, base);

        // layer 1: g1 = relu(mean1@Wl1 + h@Wr1 + bl1)
        agg_mean_kernel<<<agg_grid, 256, 0, stream>>>(H, rowptr, colidx, Mb, base);
        gemm_bf16_kernel<true, true, false><<<gemm_grid, 256, 0, stream>>>(
            Mb, Wl1t, H, Wr1t, bl1, Gb, nullptr, DENC, base);

        // layer 2 fused with emb reduction
        agg_mean_kernel<<<agg_grid, 256, 0, stream>>>(Gb, rowptr, colidx, H, base);
        gemm_bf16_kernel<true, true, true><<<gemm_grid, 256, 0, stream>>>(
            H, Wl2t, Gb, Wr2t, bl2, nullptr, emb, DENC, base);
    }

    classifier_kernel<<<NBAGS, 128, 0, stream>>>(emb, Wc1, bc1, Wc2, bc2, out);
}

// Round 8
// 564.191 us; speedup vs baseline: 1.2256x; 1.2256x over previous
//
#include <hip/hip_runtime.h>
#include <hip/hip_bf16.h>
#include <cstdint>
#include <cstddef>

// Problem constants (from reference)
#define NBAGS  16
#define NNODES 5000
#define NEDGES 160000
#define DIN    128
#define DENC   256   // == D_GNN
#define DFC    128
#define NCLS   2

#define TPB 40       // row-tiles of 128 per bag (40*128 = 5120 >= 5000)
#define HB  32       // hist blocks per bag
#define HEPB (NEDGES / HB)   // 5000 edges per hist block

typedef __attribute__((ext_vector_type(8))) short short8;
typedef __attribute__((ext_vector_type(4))) float f32x4;

static __device__ __forceinline__ ushort f2b(float v) {
    __hip_bfloat16 b = __float2bfloat16(v);   // RNE
    return *reinterpret_cast<ushort*>(&b);
}

// ---------------------------------------------------------------------------
// bf16 MFMA GEMM, bag-pinned grid: 16 bags x 40 row-tiles x 2 col-halves =
// 1280 blocks; bag = blockIdx&15 -> XCD bag%8 (same mapping as agg/cvt), so
// each bag's activations are produced and consumed on one XCD's L2.
// C[5000 x 256] per bag = act( A1@W1t^T (+ A2@W2t^T) + bias ), bf16 out.
// REDUCE=true: column-sum relu() into emb[bag][col] (g2 never materialized).
// BM=128, BN=128, BK=32; 4 waves, 4x4 mfma_f32_16x16x32_bf16 each.
// LDS rows padded to 40 elems: b128 fragment reads are 2-way (free).
// ---------------------------------------------------------------------------
template<bool DUAL, bool RELU, bool REDUCE>
__global__ __launch_bounds__(256)
void gemm_bf16_kernel(const ushort* __restrict__ A1, const ushort* __restrict__ Wt1,
                      const ushort* __restrict__ A2, const ushort* __restrict__ Wt2,
                      const float* __restrict__ bias, ushort* __restrict__ C,
                      float* __restrict__ emb, int K)
{
    constexpr int LDSP = 40;
    __shared__ __align__(16) ushort As[128 * LDSP];
    __shared__ __align__(16) ushort Bs[128 * LDSP];

    const int bx   = blockIdx.x;
    const int bag  = bx & 15;
    const int rem  = bx >> 4;          // 0..79
    const int col  = rem & 1;
    const int tile = rem >> 1;         // 0..39
    const size_t bagRow0 = (size_t)bag * NNODES;
    const int rloc0 = tile * 128;
    const int n0 = col * 128;

    const int tid  = threadIdx.x;
    const int wave = tid >> 6;
    const int lane = tid & 63;
    const int quad = lane >> 4;
    const int l16  = lane & 15;
    const int wm   = (wave >> 1) * 64;
    const int wn   = (wave & 1) * 64;

    f32x4 acc[4][4];
#pragma unroll
    for (int i = 0; i < 4; ++i)
#pragma unroll
        for (int j = 0; j < 4; ++j)
#pragma unroll
            for (int r = 0; r < 4; ++r) acc[i][j][r] = 0.f;

    const int sr = tid >> 1;           // staging row 0..127
    const int sk = (tid & 1) * 16;

    const int npass = DUAL ? 2 : 1;
    for (int pass = 0; pass < npass; ++pass) {
        const ushort* __restrict__ A = (DUAL && pass) ? A2 : A1;
        const ushort* __restrict__ W = (DUAL && pass) ? Wt2 : Wt1;

        for (int k0 = 0; k0 < K; k0 += 32) {
            {
                uint4 v0 = make_uint4(0, 0, 0, 0), v1 = make_uint4(0, 0, 0, 0);
                const int rl = rloc0 + sr;
                if (rl < NNODES) {
                    const uint4* src = (const uint4*)(A + (bagRow0 + rl) * K + k0 + sk);
                    v0 = src[0]; v1 = src[1];
                }
                *(uint4*)&As[sr * LDSP + sk]     = v0;
                *(uint4*)&As[sr * LDSP + sk + 8] = v1;
            }
            {
                const uint4* src = (const uint4*)(W + (size_t)(n0 + sr) * K + k0 + sk);
                *(uint4*)&Bs[sr * LDSP + sk]     = src[0];
                *(uint4*)&Bs[sr * LDSP + sk + 8] = src[1];
            }
            __syncthreads();

            short8 af[4], bf[4];
#pragma unroll
            for (int t = 0; t < 4; ++t) {
                af[t] = *(const short8*)&As[(wm + t * 16 + l16) * LDSP + quad * 8];
                bf[t] = *(const short8*)&Bs[(wn + t * 16 + l16) * LDSP + quad * 8];
            }
#pragma unroll
            for (int tm = 0; tm < 4; ++tm)
#pragma unroll
                for (int tn = 0; tn < 4; ++tn)
                    acc[tm][tn] = __builtin_amdgcn_mfma_f32_16x16x32_bf16(
                        af[tm], bf[tn], acc[tm][tn], 0, 0, 0);
            __syncthreads();
        }
    }

    if (!REDUCE) {
        // epilogue: bias + relu, bf16 store. C/D: row = quad*4+reg, col = l16
#pragma unroll
        for (int tm = 0; tm < 4; ++tm) {
            const int rbase = rloc0 + wm + tm * 16 + quad * 4;
#pragma unroll
            for (int reg = 0; reg < 4; ++reg) {
                const int rl = rbase + reg;
                if (rl < NNODES) {
#pragma unroll
                    for (int tn = 0; tn < 4; ++tn) {
                        const int gcol = n0 + wn + tn * 16 + l16;
                        float v = acc[tm][tn][reg] + bias[gcol];
                        if (RELU) v = fmaxf(v, 0.f);
                        C[(bagRow0 + rl) * 256 + gcol] = f2b(v);
                    }
                }
            }
        }
    } else {
        // fused column-sum epilogue -> emb[bag] (single bag per block)
        __shared__ float red[128];
        if (tid < 128) red[tid] = 0.f;
        __syncthreads();
#pragma unroll
        for (int tn = 0; tn < 4; ++tn) {
            const int cl = wn + tn * 16 + l16;            // 0..127
            const float bv = bias[n0 + cl];
            float p = 0.f;
#pragma unroll
            for (int tm = 0; tm < 4; ++tm) {
#pragma unroll
                for (int reg = 0; reg < 4; ++reg) {
                    const int rl = rloc0 + wm + tm * 16 + quad * 4 + reg;
                    float v = acc[tm][tn][reg] + bv;
                    if (RELU) v = fmaxf(v, 0.f);
                    if (rl < NNODES) p += v;
                }
            }
            atomicAdd(&red[cl], p);
        }
        __syncthreads();
        if (tid < 128)
            atomicAdd(&emb[bag * DENC + n0 + tid], red[tid]);
    }
}

// ---------------------------------------------------------------------------
// Weight convert+transpose: Wt[n*K+k] = bf16(W[k*256+n])
// ---------------------------------------------------------------------------
__global__ __launch_bounds__(256)
void wt_transpose_kernel(const float* __restrict__ W, ushort* __restrict__ Wt, int K)
{
    const int idx = blockIdx.x * 256 + threadIdx.x;
    if (idx < 256 * K) {
        const int n = idx / K;
        const int k = idx - n * K;
        Wt[idx] = f2b(W[k * 256 + n]);
    }
}

// x (fp32) -> bf16, bag-pinned (bag = bx&15). grid = 16*625, 4 elems/thread.
__global__ __launch_bounds__(256)
void cvt_bf16_kernel(const float* __restrict__ x, ushort* __restrict__ xb)
{
    const int bag = blockIdx.x & 15;
    const int chunk = blockIdx.x >> 4;
    const size_t base = (size_t)bag * (NNODES * DIN / 4);
    const int i = chunk * 256 + threadIdx.x;
    const float4 v = ((const float4*)x)[base + i];
    ushort4 o;
    o.x = f2b(v.x); o.y = f2b(v.y); o.z = f2b(v.z); o.w = f2b(v.w);
    ((ushort4*)xb)[base + i] = o;
}

// ---------------------------------------------------------------------------
// Atomic-free CSR build (counting sort with LDS histograms).
// Global device-scope atomics go to the cross-XCD coherence point (~23 G/s
// observed ceiling, 90 MB write traffic) — so count/fill were stuck at
// ~100 µs each. A 5000-entry histogram is 20 KB and fits LDS, where atomics
// are CU-local and cheap.
//   hist : per (bag,blk): LDS-histogram 5000 edges, dump to histG[bag][blk][*]
//   scan : per bag: rowptr = scan over node of block-sums; rewrite histG in
//          place as per-(blk,node) start offsets
//   place: per (bag,blk): load offsets to LDS, pos = LDS-atomicAdd, scatter
//          colidx[pos] = src (u16)
// ---------------------------------------------------------------------------
__global__ __launch_bounds__(256)
void hist_kernel(const int* __restrict__ edges, int* __restrict__ histG)
{
    const int bag = blockIdx.x & 15;
    const int blk = blockIdx.x >> 4;
    __shared__ int h[NNODES];
    for (int i = threadIdx.x; i < NNODES; i += 256) h[i] = 0;
    __syncthreads();
    const int* __restrict__ dstp = edges + (size_t)bag * 2 * NEDGES + NEDGES + blk * HEPB;
    for (int r = threadIdx.x; r < HEPB; r += 256)
        atomicAdd(&h[__builtin_nontemporal_load(&dstp[r])], 1);
    __syncthreads();
    int* __restrict__ out = histG + ((size_t)bag * HB + blk) * NNODES;
    for (int i = threadIdx.x; i < NNODES; i += 256) out[i] = h[i];
}

__global__ __launch_bounds__(1024)
void scan_kernel(int* __restrict__ histG, int* __restrict__ rowptr)
{
    const int b = blockIdx.x;
    const int t = threadIdx.x;
    __shared__ int sh[1024];
    const int CH = 5;                    // 1024*5 >= 5000
    const int base = t * CH;
    int* __restrict__ hb = histG + (size_t)b * HB * NNODES;
    int local[CH];
    int sum = 0;
#pragma unroll
    for (int i = 0; i < CH; ++i) {
        const int g = base + i;
        int s = 0;
        if (g < NNODES)
            for (int blk = 0; blk < HB; ++blk) s += hb[blk * NNODES + g];
        local[i] = s; sum += s;
    }
    sh[t] = sum;
    __syncthreads();
    for (int off = 1; off < 1024; off <<= 1) {
        const int add = (t >= off) ? sh[t - off] : 0;
        __syncthreads();
        sh[t] += add;
        __syncthreads();
    }
    int run = sh[t] - sum;               // exclusive prefix over nodes
#pragma unroll
    for (int i = 0; i < CH; ++i) {
        const int g = base + i;
        if (g < NNODES) {
            rowptr[b * (NNODES + 1) + g] = run;
            int off = run;
            for (int blk = 0; blk < HB; ++blk) {
                int* p = &hb[blk * NNODES + g];
                const int v = *p;
                *p = off;                // per-(blk,node) start offset
                off += v;
            }
        }
        run += local[i];
    }
    if (t == 1023) rowptr[b * (NNODES + 1) + NNODES] = run;  // == NEDGES
}

__global__ __launch_bounds__(256)
void place_kernel(const int* __restrict__ edges, const int* __restrict__ histG,
                  ushort* __restrict__ colidx)
{
    const int bag = blockIdx.x & 15;
    const int blk = blockIdx.x >> 4;
    __shared__ int h[NNODES];
    const int* __restrict__ offs = histG + ((size_t)bag * HB + blk) * NNODES;
    for (int i = threadIdx.x; i < NNODES; i += 256) h[i] = offs[i];
    __syncthreads();
    const int* __restrict__ eb = edges + (size_t)bag * 2 * NEDGES;
    ushort* __restrict__ co = colidx + (size_t)bag * NEDGES;
    const int e0 = blk * HEPB;
    for (int r = threadIdx.x; r < HEPB; r += 256) {
        const int s = __builtin_nontemporal_load(&eb[e0 + r]);
        const int d = __builtin_nontemporal_load(&eb[NEDGES + e0 + r]);
        const int pos = atomicAdd(&h[d], 1);     // LDS atomic, CU-local
        co[pos] = (ushort)s;
    }
}

// ---------------------------------------------------------------------------
// Mean aggregation (pull), bf16 in/out, fp32 accumulate.
// One WAVE per node: 64 lanes x uint2 = 512 B = one feature row per vmem.
// bag = blockIdx&15 -> gather source lives in the producing XCD's L2.
// ---------------------------------------------------------------------------
__global__ __launch_bounds__(256)
void agg_mean_kernel(const ushort* __restrict__ X, const int* __restrict__ rowptr,
                     const ushort* __restrict__ colidx, ushort* __restrict__ M)
{
    const int bx = blockIdx.x;
    const int bag = bx & 15;
    const int grp = bx >> 4;                  // 0..1249
    const int wave = threadIdx.x >> 6;
    const int lane = threadIdx.x & 63;
    const int node = grp * 4 + wave;

    const int* rp = rowptr + bag * (NNODES + 1);
    const int s = rp[node];
    const int e = rp[node + 1];
    const float inv = 1.0f / fmaxf((float)(e - s), 1.0f);
    const uint2* __restrict__ Xb = (const uint2*)(X + (size_t)bag * NNODES * DENC);
    const ushort* __restrict__ ci = colidx + (size_t)bag * NEDGES;

    float2 p0 = {0.f, 0.f}, p1 = {0.f, 0.f};
    int j = s;
    for (; j + 4 <= e; j += 4) {
        const int i0 = ci[j], i1 = ci[j + 1], i2 = ci[j + 2], i3 = ci[j + 3];
        const uint2 u0 = Xb[i0 * 64 + lane];
        const uint2 u1 = Xb[i1 * 64 + lane];
        const uint2 u2 = Xb[i2 * 64 + lane];
        const uint2 u3 = Xb[i3 * 64 + lane];
        p0.x += __uint_as_float(u0.x << 16); p0.y += __uint_as_float(u0.x & 0xffff0000u);
        p1.x += __uint_as_float(u0.y << 16); p1.y += __uint_as_float(u0.y & 0xffff0000u);
        p0.x += __uint_as_float(u1.x << 16); p0.y += __uint_as_float(u1.x & 0xffff0000u);
        p1.x += __uint_as_float(u1.y << 16); p1.y += __uint_as_float(u1.y & 0xffff0000u);
        p0.x += __uint_as_float(u2.x << 16); p0.y += __uint_as_float(u2.x & 0xffff0000u);
        p1.x += __uint_as_float(u2.y << 16); p1.y += __uint_as_float(u2.y & 0xffff0000u);
        p0.x += __uint_as_float(u3.x << 16); p0.y += __uint_as_float(u3.x & 0xffff0000u);
        p1.x += __uint_as_float(u3.y << 16); p1.y += __uint_as_float(u3.y & 0xffff0000u);
    }
    for (; j < e; ++j) {
        const uint2 u = Xb[ci[j] * 64 + lane];
        p0.x += __uint_as_float(u.x << 16); p0.y += __uint_as_float(u.x & 0xffff0000u);
        p1.x += __uint_as_float(u.y << 16); p1.y += __uint_as_float(u.y & 0xffff0000u);
    }
    uint2 o;
    o.x = (uint32_t)f2b(p0.x * inv) | ((uint32_t)f2b(p0.y * inv) << 16);
    o.y = (uint32_t)f2b(p1.x * inv) | ((uint32_t)f2b(p1.y * inv) << 16);
    ((uint2*)(M + ((size_t)bag * NNODES + node) * DENC))[lane] = o;
}

// ---------------------------------------------------------------------------
// classifier (fp32): out[b] = relu(emb[b]@Wc1 + bc1) @ Wc2 + bc2
// ---------------------------------------------------------------------------
__global__ __launch_bounds__(128)
void classifier_kernel(const float* __restrict__ emb, const float* __restrict__ Wc1,
                       const float* __restrict__ bc1, const float* __restrict__ Wc2,
                       const float* __restrict__ bc2, float* __restrict__ out)
{
    const int b = blockIdx.x;
    const int t = threadIdx.x;  // 128
    __shared__ float se[DENC];
    se[t] = emb[b * DENC + t];
    se[128 + t] = emb[b * DENC + 128 + t];
    __syncthreads();
    float h = bc1[t];
    for (int k = 0; k < DENC; ++k) h = fmaf(se[k], Wc1[k * DFC + t], h);
    h = fmaxf(h, 0.f);
    __shared__ float s0[128], s1[128];
    s0[t] = h * Wc2[t * NCLS + 0];
    s1[t] = h * Wc2[t * NCLS + 1];
    __syncthreads();
    for (int off = 64; off > 0; off >>= 1) {
        if (t < off) { s0[t] += s0[t + off]; s1[t] += s1[t + off]; }
        __syncthreads();
    }
    if (t == 0) {
        out[b * NCLS + 0] = s0[0] + bc2[0];
        out[b * NCLS + 1] = s1[0] + bc2[1];
    }
}

// ---------------------------------------------------------------------------
extern "C" void kernel_launch(void* const* d_in, const int* in_sizes, int n_in,
                              void* d_out, int out_size, void* d_ws, size_t ws_size,
                              hipStream_t stream)
{
    const float* x    = (const float*)d_in[0];
    const int*   edges= (const int*)d_in[1];   // int32 on device
    const float* We   = (const float*)d_in[2];
    const float* be   = (const float*)d_in[3];
    const float* Wl1  = (const float*)d_in[4];
    const float* bl1  = (const float*)d_in[5];
    const float* Wr1  = (const float*)d_in[6];
    const float* Wl2  = (const float*)d_in[7];
    const float* bl2  = (const float*)d_in[8];
    const float* Wr2  = (const float*)d_in[9];
    // d_in[10..12] = Wlp, blp, Wrp: dead (softmax over 1 cluster == 1)
    const float* Wc1  = (const float*)d_in[13];
    const float* bc1  = (const float*)d_in[14];
    const float* Wc2  = (const float*)d_in[15];
    const float* bc2  = (const float*)d_in[16];
    float* out = (float*)d_out;

    auto rnd = [](size_t v) { return (v + 255) & ~(size_t)255; };
    char* p = (char*)d_ws;
    auto alloc = [&](size_t bytes) -> char* {
        char* r = p; p += rnd(bytes); return r;
    };
    ushort* xb    = (ushort*)alloc((size_t)NBAGS * NNODES * DIN * 2);
    ushort* H     = (ushort*)alloc((size_t)NBAGS * NNODES * DENC * 2);  // h, then mean2
    ushort* Mb    = (ushort*)alloc((size_t)NBAGS * NNODES * DENC * 2);  // mean1
    ushort* Gb    = (ushort*)alloc((size_t)NBAGS * NNODES * DENC * 2);  // g1
    ushort* Wet   = (ushort*)alloc((size_t)256 * DIN * 2);
    ushort* Wl1t  = (ushort*)alloc((size_t)256 * DENC * 2);
    ushort* Wr1t  = (ushort*)alloc((size_t)256 * DENC * 2);
    ushort* Wl2t  = (ushort*)alloc((size_t)256 * DENC * 2);
    ushort* Wr2t  = (ushort*)alloc((size_t)256 * DENC * 2);
    int*    rowptr= (int*)   alloc((size_t)NBAGS * (NNODES + 1) * 4);
    int*    histG = (int*)   alloc((size_t)NBAGS * HB * NNODES * 4);   // 10.24 MB
    ushort* colidx= (ushort*)alloc((size_t)NBAGS * NEDGES * 2);
    float*  emb   = (float*) alloc((size_t)NBAGS * DENC * 4);

    // per-launch init (ws re-poisoned each call)
    hipMemsetAsync(emb, 0, (size_t)NBAGS * DENC * 4, stream);

    // conversions
    cvt_bf16_kernel<<<NBAGS * 625, 256, 0, stream>>>(x, xb);
    wt_transpose_kernel<<<(256 * DIN + 255) / 256, 256, 0, stream>>>(We, Wet, DIN);
    wt_transpose_kernel<<<(256 * DENC + 255) / 256, 256, 0, stream>>>(Wl1, Wl1t, DENC);
    wt_transpose_kernel<<<(256 * DENC + 255) / 256, 256, 0, stream>>>(Wr1, Wr1t, DENC);
    wt_transpose_kernel<<<(256 * DENC + 255) / 256, 256, 0, stream>>>(Wl2, Wl2t, DENC);
    wt_transpose_kernel<<<(256 * DENC + 255) / 256, 256, 0, stream>>>(Wr2, Wr2t, DENC);

    // CSR build (atomic-free counting sort)
    hist_kernel<<<NBAGS * HB, 256, 0, stream>>>(edges, histG);
    scan_kernel<<<NBAGS, 1024, 0, stream>>>(histG, rowptr);
    place_kernel<<<NBAGS * HB, 256, 0, stream>>>(edges, histG, colidx);

    const int gemm_grid = NBAGS * TPB * 2;     // 1280
    const int agg_grid  = NBAGS * (NNODES / 4);

    // encoder: H = relu(x @ We + be)
    gemm_bf16_kernel<false, true, false><<<gemm_grid, 256, 0, stream>>>(
        xb, Wet, nullptr, nullptr, be, H, nullptr, DIN);

    // layer 1: g1 = relu(mean1@Wl1 + h@Wr1 + bl1)
    agg_mean_kernel<<<agg_grid, 256, 0, stream>>>(H, rowptr, colidx, Mb);
    gemm_bf16_kernel<true, true, false><<<gemm_grid, 256, 0, stream>>>(
        Mb, Wl1t, H, Wr1t, bl1, Gb, nullptr, DENC);

    // layer 2 fused with emb reduction: emb += relu(mean2@Wl2 + g1@Wr2 + bl2)
    agg_mean_kernel<<<agg_grid, 256, 0, stream>>>(Gb, rowptr, colidx, H);
    gemm_bf16_kernel<true, true, true><<<gemm_grid, 256, 0, stream>>>(
        H, Wl2t, Gb, Wr2t, bl2, nullptr, emb, DENC);

    classifier_kernel<<<NBAGS, 128, 0, stream>>>(emb, Wc1, bc1, Wc2, bc2, out);
}